// Round 4
// baseline (399.751 us; speedup 1.0000x reference)
//
#include <hip/hip_runtime.h>

// LightGCN propagation, CSR-gather, bf16 intermediates, unified row space.
// R13 (from R12 @288us):
//  - agg core rebuilt: branchless masked gather rounds (always 8 gathers,
//    inactive slots read row 0 with w=0.0 -> exact +0, L1-hot) so each
//    round is one straight-line block and all loads batch into one vmcnt
//    group (old rem-cascade split them into 2-3 dependent blocks).
//  - agg1/agg2 process TWO rows per 8-lane group (row r and r+8 per wave,
//    stores stay coalesced): 2 entry loads + 16 feature loads in flight
//    per round (~288B/lane vs ~144B) -> ~2x memory-level parallelism.
//  - aggout uses the branchless single-row form.
//  - R12 pipeline otherwise unchanged.

#define N_USERS 200000
#define N_ITEMS 100000
#define N_EDGES 1000000
#define DIM 64
#define BATCH 8192
#define NTOT (N_USERS + N_ITEMS)          // 300000 rows
#define NOUT (3 * BATCH)                  // 24576 output rows
#define NPART 293                         // ceil(NTOT / 1024)
#define PLOCAL 1024

#define HA 489                            // hist/partition blocks: 8 edges/thread
#define NUNITS (NTOT * DIM / 8)           // 2.4M 8-float convert units
#define CB ((NUNITS + 1023) / 1024)       // 2344 convert blocks (32 floats/thread)
#define OB (NOUT * 8 / 256)               // 768 out_h0 / add1 blocks (8 floats/thread)
#define AB2 ((NTOT + 63) / 64)            // 4688 dual-row agg blocks (64 rows/block)
#define FB ((NOUT + 255) / 256)           // 96 flag-scatter blocks

// ---------- bf16 helpers ----------
__device__ __forceinline__ unsigned f2bf(float f) {   // round-to-nearest-even
    unsigned u = __float_as_uint(f);
    return (u + 0x7fffu + ((u >> 16) & 1u)) >> 16;
}
__device__ __forceinline__ uint2 pack4(float4 v) {
    uint2 o;
    o.x = f2bf(v.x) | (f2bf(v.y) << 16);
    o.y = f2bf(v.z) | (f2bf(v.w) << 16);
    return o;
}
__device__ __forceinline__ void fma4(float4& a, uint2 v, float w) {
    a.x += __uint_as_float(v.x << 16) * w;
    a.y += __uint_as_float(v.x & 0xffff0000u) * w;
    a.z += __uint_as_float(v.y << 16) * w;
    a.w += __uint_as_float(v.y & 0xffff0000u) * w;
}
__device__ __forceinline__ int out_bucket(int orow, const int* users,
                                          const int* pos, const int* neg) {
    int seg = orow >> 13;
    int b = orow & (BATCH - 1);
    if (seg == 0) return users[b];
    if (seg == 1) return N_USERS + pos[b];
    return N_USERS + neg[b];
}

// ---------------- A: partition hist only ----------------
__global__ void hist_kernel(const int* __restrict__ eu,
                            const int* __restrict__ ei,
                            int* __restrict__ partTotals)
{
    __shared__ int lh[NPART];
    int bid = blockIdx.x;
    for (int k = threadIdx.x; k < NPART; k += 256) lh[k] = 0;
    __syncthreads();
    int e0 = (bid * 256 + threadIdx.x) * 8;
    if (e0 < N_EDGES) {
        int4 u0 = *reinterpret_cast<const int4*>(eu + e0);
        int4 u1 = *reinterpret_cast<const int4*>(eu + e0 + 4);
        int4 i0 = *reinterpret_cast<const int4*>(ei + e0);
        int4 i1 = *reinterpret_cast<const int4*>(ei + e0 + 4);
        atomicAdd(&lh[u0.x >> 10], 1);
        atomicAdd(&lh[u0.y >> 10], 1);
        atomicAdd(&lh[u0.z >> 10], 1);
        atomicAdd(&lh[u0.w >> 10], 1);
        atomicAdd(&lh[u1.x >> 10], 1);
        atomicAdd(&lh[u1.y >> 10], 1);
        atomicAdd(&lh[u1.z >> 10], 1);
        atomicAdd(&lh[u1.w >> 10], 1);
        atomicAdd(&lh[(N_USERS + i0.x) >> 10], 1);
        atomicAdd(&lh[(N_USERS + i0.y) >> 10], 1);
        atomicAdd(&lh[(N_USERS + i0.z) >> 10], 1);
        atomicAdd(&lh[(N_USERS + i0.w) >> 10], 1);
        atomicAdd(&lh[(N_USERS + i1.x) >> 10], 1);
        atomicAdd(&lh[(N_USERS + i1.y) >> 10], 1);
        atomicAdd(&lh[(N_USERS + i1.z) >> 10], 1);
        atomicAdd(&lh[(N_USERS + i1.w) >> 10], 1);
    }
    __syncthreads();
    for (int k = threadIdx.x; k < NPART; k += 256) {
        int v = lh[k];
        if (v) atomicAdd(&partTotals[k], v);   // fire-and-forget
    }
}

// ---------------- S: scan partition totals ----------------
__global__ void part_scan_kernel(const int* __restrict__ partTotals,
                                 int* __restrict__ partStart,
                                 int* __restrict__ gcur)
{
    __shared__ int s[512];
    int t = threadIdx.x;
    s[t] = (t < NPART) ? partTotals[t] : 0;
    __syncthreads();
    for (int off = 1; off < 512; off <<= 1) {
        int x = (t >= off) ? s[t - off] : 0;
        __syncthreads();
        s[t] += x;
        __syncthreads();
    }
    if (t < NPART) {
        int st = (t == 0) ? 0 : s[t - 1];
        partStart[t] = st;
        gcur[t] = st;
    }
    if (t == NPART) partStart[NPART] = s[NPART - 1];   // == 2*N_EDGES
}

// ---------------- B: partition scatter + convert + out_h0 ----------------
// record meta = (bucket & 1023) | (col << 10);  col < 2^19, total 29 bits.
__global__ void partition_conv_kernel(const int* __restrict__ eu,
                                      const int* __restrict__ ei,
                                      const float* __restrict__ w,
                                      int* __restrict__ gcur,
                                      uint2* __restrict__ partBuf,
                                      const float4* __restrict__ uf4,
                                      const float4* __restrict__ if4,
                                      unsigned short* __restrict__ F0,
                                      const float* __restrict__ u_feat,
                                      const float* __restrict__ i_feat,
                                      const int* __restrict__ users,
                                      const int* __restrict__ pos,
                                      const int* __restrict__ neg,
                                      float* __restrict__ out)
{
    int bid = blockIdx.x, t = threadIdx.x;
    if (bid < HA) {
        __shared__ int lh[NPART];
        __shared__ int lcur[NPART];
        for (int k = t; k < NPART; k += 256) lh[k] = 0;
        __syncthreads();
        int e0 = (bid * 256 + t) * 8;
        bool act = e0 < N_EDGES;
        int4 u0, u1, i0, i1;
        if (act) {
            u0 = *reinterpret_cast<const int4*>(eu + e0);
            u1 = *reinterpret_cast<const int4*>(eu + e0 + 4);
            i0 = *reinterpret_cast<const int4*>(ei + e0);
            i1 = *reinterpret_cast<const int4*>(ei + e0 + 4);
            atomicAdd(&lh[u0.x >> 10], 1);
            atomicAdd(&lh[u0.y >> 10], 1);
            atomicAdd(&lh[u0.z >> 10], 1);
            atomicAdd(&lh[u0.w >> 10], 1);
            atomicAdd(&lh[u1.x >> 10], 1);
            atomicAdd(&lh[u1.y >> 10], 1);
            atomicAdd(&lh[u1.z >> 10], 1);
            atomicAdd(&lh[u1.w >> 10], 1);
            atomicAdd(&lh[(N_USERS + i0.x) >> 10], 1);
            atomicAdd(&lh[(N_USERS + i0.y) >> 10], 1);
            atomicAdd(&lh[(N_USERS + i0.z) >> 10], 1);
            atomicAdd(&lh[(N_USERS + i0.w) >> 10], 1);
            atomicAdd(&lh[(N_USERS + i1.x) >> 10], 1);
            atomicAdd(&lh[(N_USERS + i1.y) >> 10], 1);
            atomicAdd(&lh[(N_USERS + i1.z) >> 10], 1);
            atomicAdd(&lh[(N_USERS + i1.w) >> 10], 1);
        }
        __syncthreads();
        // reserve: one returning atomic per (block, nonempty partition)
        for (int k = t; k < NPART; k += 256) {
            int v = lh[k];
            lcur[k] = v ? atomicAdd(&gcur[k], v) : 0;
        }
        __syncthreads();
        if (act) {
            float4 wa = *reinterpret_cast<const float4*>(w + e0);
            float4 wb = *reinterpret_cast<const float4*>(w + e0 + 4);
            int us[8] = {u0.x, u0.y, u0.z, u0.w, u1.x, u1.y, u1.z, u1.w};
            int is[8] = {i0.x, i0.y, i0.z, i0.w, i1.x, i1.y, i1.z, i1.w};
            float ws[8] = {wa.x, wa.y, wa.z, wa.w, wb.x, wb.y, wb.z, wb.w};
            #pragma unroll
            for (int j = 0; j < 8; ++j) {
                int bu = us[j];
                int bi = N_USERS + is[j];
                unsigned wbits = __float_as_uint(ws[j]);
                int su = atomicAdd(&lcur[bu >> 10], 1);    // LDS
                partBuf[su] = make_uint2((unsigned)(bu & 1023) | ((unsigned)bi << 10), wbits);
                int si = atomicAdd(&lcur[bi >> 10], 1);    // LDS
                partBuf[si] = make_uint2((unsigned)(bi & 1023) | ((unsigned)bu << 10), wbits);
            }
        }
    } else if (bid < HA + CB) {
        // f32 -> bf16 convert, 32 floats/thread, 8 loads batched in flight.
        const int NU4 = N_USERS * DIM / 4;           // 3.2M float4s (user side)
        int jb = (bid - HA) * 1024 + t;              // 8-float unit index, round 0
        float4 a[4], b[4];
        #pragma unroll
        for (int c = 0; c < 4; ++c) {
            int j = jb + c * 256;
            if (j < NUNITS) {
                int f4 = j * 2;
                if (f4 < NU4) { a[c] = uf4[f4];       b[c] = uf4[f4 + 1]; }
                else          { a[c] = if4[f4 - NU4]; b[c] = if4[f4 - NU4 + 1]; }
            }
        }
        #pragma unroll
        for (int c = 0; c < 4; ++c) {
            int j = jb + c * 256;
            if (j < NUNITS) {
                uint2 pa = pack4(a[c]), pb = pack4(b[c]);
                *reinterpret_cast<uint4*>(F0 + (size_t)j * 8) =
                    make_uint4(pa.x, pa.y, pb.x, pb.y);
            }
        }
    } else {
        // out = 0.25 * h0 at gathered rows, 8 floats/thread (2 loads in flight)
        int idx = (bid - HA - CB) * 256 + t;         // [0, NOUT*8) exactly
        int row = idx >> 3;
        if (row >= NOUT) return;
        int d8 = (idx & 7) << 3;
        int seg = row >> 13;
        int b = row & (BATCH - 1);
        const float* src;
        if (seg == 0)      src = u_feat + (size_t)users[b] * DIM;
        else if (seg == 1) src = i_feat + (size_t)pos[b]   * DIM;
        else               src = i_feat + (size_t)neg[b]   * DIM;
        float4 v0 = *reinterpret_cast<const float4*>(src + d8);
        float4 v1 = *reinterpret_cast<const float4*>(src + d8 + 4);
        v0.x *= 0.25f; v0.y *= 0.25f; v0.z *= 0.25f; v0.w *= 0.25f;
        v1.x *= 0.25f; v1.y *= 0.25f; v1.z *= 0.25f; v1.w *= 0.25f;
        float* op = out + (size_t)row * DIM + d8;
        *reinterpret_cast<float4*>(op) = v0;
        *reinterpret_cast<float4*>(op + 4) = v1;
    }
}

// ---------------- C: per-partition CSR build (rp + entries) ----------------
__global__ void __launch_bounds__(1024)
build_csr_kernel(const int* __restrict__ partStart,
                 const uint2* __restrict__ partBuf,
                 int* __restrict__ rp,
                 int2* __restrict__ entries)
{
    __shared__ int h[PLOCAL];
    __shared__ int s[PLOCAL];
    __shared__ int cur[PLOCAL];
    int p = blockIdx.x, t = threadIdx.x;
    int base = partStart[p], end = partStart[p + 1];
    h[t] = 0;
    __syncthreads();
    for (int r = base + t; r < end; r += 1024)
        atomicAdd(&h[partBuf[r].x & 1023], 1);
    __syncthreads();
    s[t] = h[t];
    __syncthreads();
    for (int off = 1; off < 1024; off <<= 1) {
        int x = (t >= off) ? s[t - off] : 0;
        __syncthreads();
        s[t] += x;
        __syncthreads();
    }
    int c0 = base + s[t] - h[t];        // exclusive scan -> bucket start
    cur[t] = c0;
    int gb = p * PLOCAL + t;
    if (gb <= NTOT) rp[gb] = c0;
    __syncthreads();
    for (int r = base + t; r < end; r += 1024) {
        uint2 rec = partBuf[r];
        int slot = atomicAdd(&cur[rec.x & 1023], 1);   // LDS
        entries[slot] = make_int2((int)(rec.x >> 10), (int)rec.y);
    }
}

// ---------------- agg core: branchless masked gather rounds ----------------
// e == {0,0} for inactive slots: col 0, w 0.0f -> fma adds exact +0,
// dummy read hits the L1-hot row 0. No rem-cascade -> one straight-line
// block per round, all loads batch into one vmcnt group.
#define GATHE(e, idx, aL, aH)                                                 \
    {                                                                         \
        int c = __shfl((e).x, gb + (idx));                                    \
        float ww = __int_as_float(__shfl((e).y, gb + (idx)));                 \
        uint4 v = *reinterpret_cast<const uint4*>(                            \
            src + (size_t)c * DIM + l8 * 8);                                  \
        fma4(aL, make_uint2(v.x, v.y), ww);                                   \
        fma4(aH, make_uint2(v.z, v.w), ww);                                   \
    }

// two rows per 8-lane group: 2 entry loads + 16 gathers in flight per round
__device__ __forceinline__ void agg_dual(int rowA, int rowB, int l8, int gb,
                                         const int* __restrict__ rp,
                                         const int2* __restrict__ entries,
                                         const unsigned short* __restrict__ src,
                                         float4& sAL, float4& sAH,
                                         float4& sBL, float4& sBH)
{
    int begA = rp[rowA], cntA = rp[rowA + 1] - begA;
    int begB = rp[rowB], cntB = rp[rowB + 1] - begB;
    float4 aL0 = {0,0,0,0}, aH0 = {0,0,0,0}, aL1 = {0,0,0,0}, aH1 = {0,0,0,0};
    float4 bL0 = {0,0,0,0}, bH0 = {0,0,0,0}, bL1 = {0,0,0,0}, bH1 = {0,0,0,0};
    int mx = cntA > cntB ? cntA : cntB;
    for (int base = 0; base < mx; base += 8) {
        int2 eA = make_int2(0, 0), eB = make_int2(0, 0);
        if (base + l8 < cntA) eA = entries[begA + base + l8];
        if (base + l8 < cntB) eB = entries[begB + base + l8];
        GATHE(eA, 0, aL0, aH0) GATHE(eB, 0, bL0, bH0)
        GATHE(eA, 1, aL1, aH1) GATHE(eB, 1, bL1, bH1)
        GATHE(eA, 2, aL0, aH0) GATHE(eB, 2, bL0, bH0)
        GATHE(eA, 3, aL1, aH1) GATHE(eB, 3, bL1, bH1)
        GATHE(eA, 4, aL0, aH0) GATHE(eB, 4, bL0, bH0)
        GATHE(eA, 5, aL1, aH1) GATHE(eB, 5, bL1, bH1)
        GATHE(eA, 6, aL0, aH0) GATHE(eB, 6, bL0, bH0)
        GATHE(eA, 7, aL1, aH1) GATHE(eB, 7, bL1, bH1)
    }
    sAL.x = aL0.x + aL1.x; sAL.y = aL0.y + aL1.y;
    sAL.z = aL0.z + aL1.z; sAL.w = aL0.w + aL1.w;
    sAH.x = aH0.x + aH1.x; sAH.y = aH0.y + aH1.y;
    sAH.z = aH0.z + aH1.z; sAH.w = aH0.w + aH1.w;
    sBL.x = bL0.x + bL1.x; sBL.y = bL0.y + bL1.y;
    sBL.z = bL0.z + bL1.z; sBL.w = bL0.w + bL1.w;
    sBH.x = bH0.x + bH1.x; sBH.y = bH0.y + bH1.y;
    sBH.z = bH0.z + bH1.z; sBH.w = bH0.w + bH1.w;
}

// single-row branchless form (aggout)
__device__ __forceinline__ void agg_one(int row, int l8, int gb,
                                        const int* __restrict__ rp,
                                        const int2* __restrict__ entries,
                                        const unsigned short* __restrict__ src,
                                        float4& sL, float4& sH)
{
    int beg = rp[row], cnt = rp[row + 1] - beg;
    float4 a0L = {0,0,0,0}, a0H = {0,0,0,0}, a1L = {0,0,0,0}, a1H = {0,0,0,0};
    for (int base = 0; base < cnt; base += 8) {
        int2 e = make_int2(0, 0);
        if (base + l8 < cnt) e = entries[beg + base + l8];
        GATHE(e, 0, a0L, a0H)
        GATHE(e, 1, a1L, a1H)
        GATHE(e, 2, a0L, a0H)
        GATHE(e, 3, a1L, a1H)
        GATHE(e, 4, a0L, a0H)
        GATHE(e, 5, a1L, a1H)
        GATHE(e, 6, a0L, a0H)
        GATHE(e, 7, a1L, a1H)
    }
    sL.x = a0L.x + a1L.x; sL.y = a0L.y + a1L.y;
    sL.z = a0L.z + a1L.z; sL.w = a0L.w + a1L.w;
    sH.x = a0H.x + a1H.x; sH.y = a0H.y + a1H.y;
    sH.z = a0H.z + a1H.z; sH.w = a0H.w + a1H.w;
}

// ---------------- layer 1 (all rows) + flag scatter ----------------
__global__ void agg1_flag_kernel(const int* __restrict__ rp,
                                 const int2* __restrict__ entries,
                                 const unsigned short* __restrict__ F0,
                                 unsigned short* __restrict__ H1,
                                 const int* __restrict__ users,
                                 const int* __restrict__ pos,
                                 const int* __restrict__ neg,
                                 int* __restrict__ flags)
{
    int bid = blockIdx.x;
    if (bid < AB2) {
        int gid = bid * 256 + threadIdx.x;
        int lane = gid & 63;
        int l8 = lane & 7;
        int gb = lane & 56;
        // wave covers 16 consecutive rows; group k takes rows base+k, base+k+8
        int rowA = (gid >> 6) * 16 + (lane >> 3);
        if (rowA >= NTOT) return;           // wave-uniform (NTOT % 16 == 0)
        int rowB = rowA + 8;
        float4 sAL, sAH, sBL, sBH;
        agg_dual(rowA, rowB, l8, gb, rp, entries, F0, sAL, sAH, sBL, sBH);
        uint2 pL = pack4(sAL), pH = pack4(sAH);
        *reinterpret_cast<uint4*>(H1 + (size_t)rowA * DIM + l8 * 8) =
            make_uint4(pL.x, pL.y, pH.x, pH.y);
        pL = pack4(sBL); pH = pack4(sBH);
        *reinterpret_cast<uint4*>(H1 + (size_t)rowB * DIM + l8 * 8) =
            make_uint4(pL.x, pL.y, pH.x, pH.y);
    } else {
        int t = (bid - AB2) * 256 + threadIdx.x;
        if (t >= NOUT) return;
        int bucket = out_bucket(t, users, pos, neg);
        flags[bucket] = 1;
        int beg = rp[bucket], end = rp[bucket + 1];
        for (int k = beg; k < end; ++k)
            flags[entries[k].x] = 1;
    }
}

// ---------------- compact flags -> row list ----------------
__global__ void compact_kernel(const int* __restrict__ flags,
                               int* __restrict__ list,
                               int* __restrict__ count)
{
    int t = blockIdx.x * blockDim.x + threadIdx.x;
    int idx = t * 4;
    if (idx >= NTOT) return;
    int4 f = *reinterpret_cast<const int4*>(flags + idx);
    int loc[4]; int k = 0;
    if (f.x) loc[k++] = idx;
    if (f.y) loc[k++] = idx + 1;
    if (f.z) loc[k++] = idx + 2;
    if (f.w) loc[k++] = idx + 3;
    if (k) {
        int base = atomicAdd(count, k);
        for (int m = 0; m < k; ++m) list[base + m] = loc[m];
    }
}

// ---------------- layer 2 (listed rows only) + out += 0.25*H1 ----------------
__global__ void agg2_add1_kernel(const int* __restrict__ rp,
                                 const int2* __restrict__ entries,
                                 const unsigned short* __restrict__ H1,
                                 unsigned short* __restrict__ H2,
                                 const int* __restrict__ list,
                                 const int* __restrict__ count,
                                 const int* __restrict__ users,
                                 const int* __restrict__ pos,
                                 const int* __restrict__ neg,
                                 float* __restrict__ out)
{
    int bid = blockIdx.x;
    if (bid < AB2) {
        int gid = bid * 256 + threadIdx.x;
        int lane = gid & 63;
        int l8 = lane & 7;
        int gb = lane & 56;
        int n = *count;
        int idxA = (gid >> 6) * 16 + (lane >> 3);
        int idxB = idxA + 8;
        if (idxA >= n) return;              // group-uniform
        bool hasB = idxB < n;
        int rowA = list[idxA];
        int rowB = hasB ? list[idxB] : rowA;   // duplicate at tail, B discarded
        float4 sAL, sAH, sBL, sBH;
        agg_dual(rowA, rowB, l8, gb, rp, entries, H1, sAL, sAH, sBL, sBH);
        uint2 pL = pack4(sAL), pH = pack4(sAH);
        *reinterpret_cast<uint4*>(H2 + (size_t)rowA * DIM + l8 * 8) =
            make_uint4(pL.x, pL.y, pH.x, pH.y);
        if (hasB) {
            pL = pack4(sBL); pH = pack4(sBH);
            *reinterpret_cast<uint4*>(H2 + (size_t)rowB * DIM + l8 * 8) =
                make_uint4(pL.x, pL.y, pH.x, pH.y);
        }
    } else {
        // out += 0.25 * H1[bucket], 8 floats/thread (matches OB = NOUT*8/256)
        int idx = (bid - AB2) * 256 + threadIdx.x;   // [0, NOUT*8)
        int row = idx >> 3;
        if (row >= NOUT) return;
        int d8 = (idx & 7) << 3;
        int bucket = out_bucket(row, users, pos, neg);
        uint4 v = *reinterpret_cast<const uint4*>(H1 + (size_t)bucket * DIM + d8);
        float* op = out + (size_t)row * DIM + d8;
        float4 o0 = *reinterpret_cast<const float4*>(op);
        float4 o1 = *reinterpret_cast<const float4*>(op + 4);
        o0.x += 0.25f * __uint_as_float(v.x << 16);
        o0.y += 0.25f * __uint_as_float(v.x & 0xffff0000u);
        o0.z += 0.25f * __uint_as_float(v.y << 16);
        o0.w += 0.25f * __uint_as_float(v.y & 0xffff0000u);
        o1.x += 0.25f * __uint_as_float(v.z << 16);
        o1.y += 0.25f * __uint_as_float(v.z & 0xffff0000u);
        o1.z += 0.25f * __uint_as_float(v.w << 16);
        o1.w += 0.25f * __uint_as_float(v.w & 0xffff0000u);
        *reinterpret_cast<float4*>(op) = o0;
        *reinterpret_cast<float4*>(op + 4) = o1;
    }
}

// ---------------- layer 3 at output rows, H2 add fused IN-THREAD ----------------
__global__ void aggout_add2_kernel(const int* __restrict__ rp,
                                   const int2* __restrict__ entries,
                                   const unsigned short* __restrict__ H2,
                                   const int* __restrict__ users,
                                   const int* __restrict__ pos,
                                   const int* __restrict__ neg,
                                   float* __restrict__ out)
{
    int gid = blockIdx.x * 256 + threadIdx.x;
    int lane = gid & 63;
    int l8 = lane & 7;
    int gb = lane & 56;
    int orow = gid >> 3;
    if (orow >= NOUT) return;
    int bucket = out_bucket(orow, users, pos, neg);
    float4 sL, sH;
    agg_one(bucket, l8, gb, rp, entries, H2, sL, sH);
    uint4 v = *reinterpret_cast<const uint4*>(H2 + (size_t)bucket * DIM + l8 * 8);
    sL.x += __uint_as_float(v.x << 16);
    sL.y += __uint_as_float(v.x & 0xffff0000u);
    sL.z += __uint_as_float(v.y << 16);
    sL.w += __uint_as_float(v.y & 0xffff0000u);
    sH.x += __uint_as_float(v.z << 16);
    sH.y += __uint_as_float(v.z & 0xffff0000u);
    sH.z += __uint_as_float(v.w << 16);
    sH.w += __uint_as_float(v.w & 0xffff0000u);
    float* op = out + (size_t)orow * DIM + l8 * 8;
    float4 o0 = *reinterpret_cast<const float4*>(op);
    float4 o1 = *reinterpret_cast<const float4*>(op + 4);
    o0.x += 0.25f * sL.x; o0.y += 0.25f * sL.y;
    o0.z += 0.25f * sL.z; o0.w += 0.25f * sL.w;
    o1.x += 0.25f * sH.x; o1.y += 0.25f * sH.y;
    o1.z += 0.25f * sH.z; o1.w += 0.25f * sH.w;
    *reinterpret_cast<float4*>(op) = o0;
    *reinterpret_cast<float4*>(op + 4) = o1;
}

extern "C" void kernel_launch(void* const* d_in, const int* in_sizes, int n_in,
                              void* d_out, int out_size, void* d_ws, size_t ws_size,
                              hipStream_t stream)
{
    const float* user_feat = (const float*)d_in[0];
    const float* item_feat = (const float*)d_in[1];
    const int*   eu        = (const int*)d_in[2];
    const int*   ei        = (const int*)d_in[3];
    const float* norm      = (const float*)d_in[4];
    const int*   users     = (const int*)d_in[5];
    const int*   pos       = (const int*)d_in[6];
    const int*   neg       = (const int*)d_in[7];
    float* out = (float*)d_out;

    auto align256 = [](size_t x) { return (x + 255) & ~(size_t)255; };
    const size_t hBytes = (size_t)NTOT * DIM * sizeof(unsigned short);  // 38.4 MB

    char* p = (char*)d_ws;
    unsigned short* F0 = (unsigned short*)p; p += align256(hBytes);
    unsigned short* H1 = (unsigned short*)p; p += align256(hBytes);
    unsigned short* H2 = (unsigned short*)p; p += align256(hBytes);
    // memset region: partTotals(512 pad) | flags(NTOT) | count(16 pad)
    int* partTotals = (int*)p; p += align256((size_t)(512 + NTOT + 16) * 4);
    int* flags = partTotals + 512;
    int* count = flags + NTOT;
    int*  partStart = (int*)p;  p += align256(512 * 4);
    int*  gcur      = (int*)p;  p += align256(512 * 4);
    int*  rp        = (int*)p;  p += align256((size_t)(NTOT + 1) * 4);
    uint2* partBuf  = (uint2*)p; p += align256((size_t)2 * N_EDGES * 8);
    int*  list      = (int*)p;  p += align256((size_t)NTOT * 4);
    int2* entries   = (int2*)p; p += align256((size_t)2 * N_EDGES * 8);
    // total ~150 MB

    hipMemsetAsync(partTotals, 0, (size_t)(512 + NTOT + 16) * 4, stream);

    // A: partition hist only (short critical-path head)
    hist_kernel<<<HA, 256, 0, stream>>>(eu, ei, partTotals);

    // S: scan partition totals
    part_scan_kernel<<<1, 512, 0, stream>>>(partTotals, partStart, gcur);

    // B: partition scatter + f32->bf16 convert + out_h0 (overlapped)
    partition_conv_kernel<<<HA + CB + OB, 256, 0, stream>>>(
        eu, ei, norm, gcur, partBuf,
        (const float4*)user_feat, (const float4*)item_feat, F0,
        user_feat, item_feat, users, pos, neg, out);

    // C: per-partition CSR build (writes rp + entries), 1024 thr/block
    build_csr_kernel<<<NPART, 1024, 0, stream>>>(partStart, partBuf, rp, entries);

    // layer 1 (all rows, dual-row groups) + flag scatter for needed-H2 set
    agg1_flag_kernel<<<AB2 + FB, 256, 0, stream>>>(
        rp, entries, F0, H1, users, pos, neg, flags);

    compact_kernel<<<(NTOT / 4 + 255) / 256, 256, 0, stream>>>(flags, list, count);

    // layer 2 (listed rows, dual-row groups) + out += 0.25*H1
    agg2_add1_kernel<<<AB2 + OB, 256, 0, stream>>>(
        rp, entries, H1, H2, list, count, users, pos, neg, out);

    // layer 3 at output rows with in-thread H2 add
    aggout_add2_kernel<<<NOUT / 32, 256, 0, stream>>>(
        rp, entries, H2, users, pos, neg, out);
}

// Round 5
// 284.805 us; speedup vs baseline: 1.4036x; 1.4036x over previous
//
#include <hip/hip_runtime.h>

// LightGCN propagation, CSR-gather, bf16 intermediates, unified row space.
// R14 (from R13 FAILED @400us — dual-row spilled accumulators to scratch:
// VGPR 64 cap, occupancy 35%, WRITE_SIZE 43->231MB symmetric spill traffic):
//  - REVERT to R12 agg structure: 8 lanes/row, 8 rows/wave, 4 float4 accs.
//  - KEEP branchless masked rounds only: always 8 gathers/round, inactive
//    slots read row 0 with w=0.0 (exact +0, L1-hot). Removes the rem-cascade
//    so each round is one straight-line block, one vmcnt batch.
//  - R12 pipeline otherwise unchanged.

#define N_USERS 200000
#define N_ITEMS 100000
#define N_EDGES 1000000
#define DIM 64
#define BATCH 8192
#define NTOT (N_USERS + N_ITEMS)          // 300000 rows
#define NOUT (3 * BATCH)                  // 24576 output rows
#define NPART 293                         // ceil(NTOT / 1024)
#define PLOCAL 1024

#define HA 489                            // hist/partition blocks: 8 edges/thread
#define NUNITS (NTOT * DIM / 8)           // 2.4M 8-float convert units
#define CB ((NUNITS + 1023) / 1024)       // 2344 convert blocks (32 floats/thread)
#define OB (NOUT * 8 / 256)               // 768 out_h0 / add1 blocks (8 floats/thread)
#define AB8 (NTOT / 32)                   // 9375 agg blocks (32 rows/block, 8 lanes/row)
#define FB ((NOUT + 255) / 256)           // 96 flag-scatter blocks

// ---------- bf16 helpers ----------
__device__ __forceinline__ unsigned f2bf(float f) {   // round-to-nearest-even
    unsigned u = __float_as_uint(f);
    return (u + 0x7fffu + ((u >> 16) & 1u)) >> 16;
}
__device__ __forceinline__ uint2 pack4(float4 v) {
    uint2 o;
    o.x = f2bf(v.x) | (f2bf(v.y) << 16);
    o.y = f2bf(v.z) | (f2bf(v.w) << 16);
    return o;
}
__device__ __forceinline__ void fma4(float4& a, uint2 v, float w) {
    a.x += __uint_as_float(v.x << 16) * w;
    a.y += __uint_as_float(v.x & 0xffff0000u) * w;
    a.z += __uint_as_float(v.y << 16) * w;
    a.w += __uint_as_float(v.y & 0xffff0000u) * w;
}
__device__ __forceinline__ int out_bucket(int orow, const int* users,
                                          const int* pos, const int* neg) {
    int seg = orow >> 13;
    int b = orow & (BATCH - 1);
    if (seg == 0) return users[b];
    if (seg == 1) return N_USERS + pos[b];
    return N_USERS + neg[b];
}

// ---------------- A: partition hist only ----------------
__global__ void hist_kernel(const int* __restrict__ eu,
                            const int* __restrict__ ei,
                            int* __restrict__ partTotals)
{
    __shared__ int lh[NPART];
    int bid = blockIdx.x;
    for (int k = threadIdx.x; k < NPART; k += 256) lh[k] = 0;
    __syncthreads();
    int e0 = (bid * 256 + threadIdx.x) * 8;
    if (e0 < N_EDGES) {
        int4 u0 = *reinterpret_cast<const int4*>(eu + e0);
        int4 u1 = *reinterpret_cast<const int4*>(eu + e0 + 4);
        int4 i0 = *reinterpret_cast<const int4*>(ei + e0);
        int4 i1 = *reinterpret_cast<const int4*>(ei + e0 + 4);
        atomicAdd(&lh[u0.x >> 10], 1);
        atomicAdd(&lh[u0.y >> 10], 1);
        atomicAdd(&lh[u0.z >> 10], 1);
        atomicAdd(&lh[u0.w >> 10], 1);
        atomicAdd(&lh[u1.x >> 10], 1);
        atomicAdd(&lh[u1.y >> 10], 1);
        atomicAdd(&lh[u1.z >> 10], 1);
        atomicAdd(&lh[u1.w >> 10], 1);
        atomicAdd(&lh[(N_USERS + i0.x) >> 10], 1);
        atomicAdd(&lh[(N_USERS + i0.y) >> 10], 1);
        atomicAdd(&lh[(N_USERS + i0.z) >> 10], 1);
        atomicAdd(&lh[(N_USERS + i0.w) >> 10], 1);
        atomicAdd(&lh[(N_USERS + i1.x) >> 10], 1);
        atomicAdd(&lh[(N_USERS + i1.y) >> 10], 1);
        atomicAdd(&lh[(N_USERS + i1.z) >> 10], 1);
        atomicAdd(&lh[(N_USERS + i1.w) >> 10], 1);
    }
    __syncthreads();
    for (int k = threadIdx.x; k < NPART; k += 256) {
        int v = lh[k];
        if (v) atomicAdd(&partTotals[k], v);   // fire-and-forget
    }
}

// ---------------- S: scan partition totals ----------------
__global__ void part_scan_kernel(const int* __restrict__ partTotals,
                                 int* __restrict__ partStart,
                                 int* __restrict__ gcur)
{
    __shared__ int s[512];
    int t = threadIdx.x;
    s[t] = (t < NPART) ? partTotals[t] : 0;
    __syncthreads();
    for (int off = 1; off < 512; off <<= 1) {
        int x = (t >= off) ? s[t - off] : 0;
        __syncthreads();
        s[t] += x;
        __syncthreads();
    }
    if (t < NPART) {
        int st = (t == 0) ? 0 : s[t - 1];
        partStart[t] = st;
        gcur[t] = st;
    }
    if (t == NPART) partStart[NPART] = s[NPART - 1];   // == 2*N_EDGES
}

// ---------------- B: partition scatter + convert + out_h0 ----------------
// record meta = (bucket & 1023) | (col << 10);  col < 2^19, total 29 bits.
__global__ void partition_conv_kernel(const int* __restrict__ eu,
                                      const int* __restrict__ ei,
                                      const float* __restrict__ w,
                                      int* __restrict__ gcur,
                                      uint2* __restrict__ partBuf,
                                      const float4* __restrict__ uf4,
                                      const float4* __restrict__ if4,
                                      unsigned short* __restrict__ F0,
                                      const float* __restrict__ u_feat,
                                      const float* __restrict__ i_feat,
                                      const int* __restrict__ users,
                                      const int* __restrict__ pos,
                                      const int* __restrict__ neg,
                                      float* __restrict__ out)
{
    int bid = blockIdx.x, t = threadIdx.x;
    if (bid < HA) {
        __shared__ int lh[NPART];
        __shared__ int lcur[NPART];
        for (int k = t; k < NPART; k += 256) lh[k] = 0;
        __syncthreads();
        int e0 = (bid * 256 + t) * 8;
        bool act = e0 < N_EDGES;
        int4 u0, u1, i0, i1;
        if (act) {
            u0 = *reinterpret_cast<const int4*>(eu + e0);
            u1 = *reinterpret_cast<const int4*>(eu + e0 + 4);
            i0 = *reinterpret_cast<const int4*>(ei + e0);
            i1 = *reinterpret_cast<const int4*>(ei + e0 + 4);
            atomicAdd(&lh[u0.x >> 10], 1);
            atomicAdd(&lh[u0.y >> 10], 1);
            atomicAdd(&lh[u0.z >> 10], 1);
            atomicAdd(&lh[u0.w >> 10], 1);
            atomicAdd(&lh[u1.x >> 10], 1);
            atomicAdd(&lh[u1.y >> 10], 1);
            atomicAdd(&lh[u1.z >> 10], 1);
            atomicAdd(&lh[u1.w >> 10], 1);
            atomicAdd(&lh[(N_USERS + i0.x) >> 10], 1);
            atomicAdd(&lh[(N_USERS + i0.y) >> 10], 1);
            atomicAdd(&lh[(N_USERS + i0.z) >> 10], 1);
            atomicAdd(&lh[(N_USERS + i0.w) >> 10], 1);
            atomicAdd(&lh[(N_USERS + i1.x) >> 10], 1);
            atomicAdd(&lh[(N_USERS + i1.y) >> 10], 1);
            atomicAdd(&lh[(N_USERS + i1.z) >> 10], 1);
            atomicAdd(&lh[(N_USERS + i1.w) >> 10], 1);
        }
        __syncthreads();
        // reserve: one returning atomic per (block, nonempty partition)
        for (int k = t; k < NPART; k += 256) {
            int v = lh[k];
            lcur[k] = v ? atomicAdd(&gcur[k], v) : 0;
        }
        __syncthreads();
        if (act) {
            float4 wa = *reinterpret_cast<const float4*>(w + e0);
            float4 wb = *reinterpret_cast<const float4*>(w + e0 + 4);
            int us[8] = {u0.x, u0.y, u0.z, u0.w, u1.x, u1.y, u1.z, u1.w};
            int is[8] = {i0.x, i0.y, i0.z, i0.w, i1.x, i1.y, i1.z, i1.w};
            float ws[8] = {wa.x, wa.y, wa.z, wa.w, wb.x, wb.y, wb.z, wb.w};
            #pragma unroll
            for (int j = 0; j < 8; ++j) {
                int bu = us[j];
                int bi = N_USERS + is[j];
                unsigned wbits = __float_as_uint(ws[j]);
                int su = atomicAdd(&lcur[bu >> 10], 1);    // LDS
                partBuf[su] = make_uint2((unsigned)(bu & 1023) | ((unsigned)bi << 10), wbits);
                int si = atomicAdd(&lcur[bi >> 10], 1);    // LDS
                partBuf[si] = make_uint2((unsigned)(bi & 1023) | ((unsigned)bu << 10), wbits);
            }
        }
    } else if (bid < HA + CB) {
        // f32 -> bf16 convert, 32 floats/thread, 8 loads batched in flight.
        const int NU4 = N_USERS * DIM / 4;           // 3.2M float4s (user side)
        int jb = (bid - HA) * 1024 + t;              // 8-float unit index, round 0
        float4 a[4], b[4];
        #pragma unroll
        for (int c = 0; c < 4; ++c) {
            int j = jb + c * 256;
            if (j < NUNITS) {
                int f4 = j * 2;
                if (f4 < NU4) { a[c] = uf4[f4];       b[c] = uf4[f4 + 1]; }
                else          { a[c] = if4[f4 - NU4]; b[c] = if4[f4 - NU4 + 1]; }
            }
        }
        #pragma unroll
        for (int c = 0; c < 4; ++c) {
            int j = jb + c * 256;
            if (j < NUNITS) {
                uint2 pa = pack4(a[c]), pb = pack4(b[c]);
                *reinterpret_cast<uint4*>(F0 + (size_t)j * 8) =
                    make_uint4(pa.x, pa.y, pb.x, pb.y);
            }
        }
    } else {
        // out = 0.25 * h0 at gathered rows, 8 floats/thread (2 loads in flight)
        int idx = (bid - HA - CB) * 256 + t;         // [0, NOUT*8) exactly
        int row = idx >> 3;
        if (row >= NOUT) return;
        int d8 = (idx & 7) << 3;
        int seg = row >> 13;
        int b = row & (BATCH - 1);
        const float* src;
        if (seg == 0)      src = u_feat + (size_t)users[b] * DIM;
        else if (seg == 1) src = i_feat + (size_t)pos[b]   * DIM;
        else               src = i_feat + (size_t)neg[b]   * DIM;
        float4 v0 = *reinterpret_cast<const float4*>(src + d8);
        float4 v1 = *reinterpret_cast<const float4*>(src + d8 + 4);
        v0.x *= 0.25f; v0.y *= 0.25f; v0.z *= 0.25f; v0.w *= 0.25f;
        v1.x *= 0.25f; v1.y *= 0.25f; v1.z *= 0.25f; v1.w *= 0.25f;
        float* op = out + (size_t)row * DIM + d8;
        *reinterpret_cast<float4*>(op) = v0;
        *reinterpret_cast<float4*>(op + 4) = v1;
    }
}

// ---------------- C: per-partition CSR build (rp + entries) ----------------
__global__ void __launch_bounds__(1024)
build_csr_kernel(const int* __restrict__ partStart,
                 const uint2* __restrict__ partBuf,
                 int* __restrict__ rp,
                 int2* __restrict__ entries)
{
    __shared__ int h[PLOCAL];
    __shared__ int s[PLOCAL];
    __shared__ int cur[PLOCAL];
    int p = blockIdx.x, t = threadIdx.x;
    int base = partStart[p], end = partStart[p + 1];
    h[t] = 0;
    __syncthreads();
    for (int r = base + t; r < end; r += 1024)
        atomicAdd(&h[partBuf[r].x & 1023], 1);
    __syncthreads();
    s[t] = h[t];
    __syncthreads();
    for (int off = 1; off < 1024; off <<= 1) {
        int x = (t >= off) ? s[t - off] : 0;
        __syncthreads();
        s[t] += x;
        __syncthreads();
    }
    int c0 = base + s[t] - h[t];        // exclusive scan -> bucket start
    cur[t] = c0;
    int gb = p * PLOCAL + t;
    if (gb <= NTOT) rp[gb] = c0;
    __syncthreads();
    for (int r = base + t; r < end; r += 1024) {
        uint2 rec = partBuf[r];
        int slot = atomicAdd(&cur[rec.x & 1023], 1);   // LDS
        entries[slot] = make_int2((int)(rec.x >> 10), (int)rec.y);
    }
}

// ---------------- agg core: branchless masked rounds, 8 lanes/row ----------------
// e == {0,0} for inactive slots: col 0, w 0.0f -> fma adds exact +0,
// dummy read hits the L1-hot row 0. One straight-line block per round,
// all 8 gathers batch into one vmcnt group. 4 float4 accs (16 VGPR).
#define GATHE(e, idx, aL, aH)                                                 \
    {                                                                         \
        int c = __shfl((e).x, gb + (idx));                                    \
        float ww = __int_as_float(__shfl((e).y, gb + (idx)));                 \
        uint4 v = *reinterpret_cast<const uint4*>(                            \
            src + (size_t)c * DIM + l8 * 8);                                  \
        fma4(aL, make_uint2(v.x, v.y), ww);                                   \
        fma4(aH, make_uint2(v.z, v.w), ww);                                   \
    }

__device__ __forceinline__ void agg_row8(int row, int l8, int gb,
                                         const int* __restrict__ rp,
                                         const int2* __restrict__ entries,
                                         const unsigned short* __restrict__ src,
                                         float4& sL, float4& sH)
{
    int beg = rp[row], cnt = rp[row + 1] - beg;
    float4 a0L = {0,0,0,0}, a0H = {0,0,0,0}, a1L = {0,0,0,0}, a1H = {0,0,0,0};
    for (int base = 0; base < cnt; base += 8) {
        int2 e = make_int2(0, 0);
        if (base + l8 < cnt) e = entries[beg + base + l8];
        GATHE(e, 0, a0L, a0H)
        GATHE(e, 1, a1L, a1H)
        GATHE(e, 2, a0L, a0H)
        GATHE(e, 3, a1L, a1H)
        GATHE(e, 4, a0L, a0H)
        GATHE(e, 5, a1L, a1H)
        GATHE(e, 6, a0L, a0H)
        GATHE(e, 7, a1L, a1H)
    }
    sL.x = a0L.x + a1L.x; sL.y = a0L.y + a1L.y;
    sL.z = a0L.z + a1L.z; sL.w = a0L.w + a1L.w;
    sH.x = a0H.x + a1H.x; sH.y = a0H.y + a1H.y;
    sH.z = a0H.z + a1H.z; sH.w = a0H.w + a1H.w;
}

// ---------------- layer 1 (all rows) + flag scatter ----------------
__global__ void agg1_flag_kernel(const int* __restrict__ rp,
                                 const int2* __restrict__ entries,
                                 const unsigned short* __restrict__ F0,
                                 unsigned short* __restrict__ H1,
                                 const int* __restrict__ users,
                                 const int* __restrict__ pos,
                                 const int* __restrict__ neg,
                                 int* __restrict__ flags)
{
    int bid = blockIdx.x;
    if (bid < AB8) {
        int gid = bid * 256 + threadIdx.x;
        int lane = gid & 63;
        int l8 = lane & 7;
        int gb = lane & 56;
        int row = gid >> 3;
        if (row >= NTOT) return;
        float4 sL, sH;
        agg_row8(row, l8, gb, rp, entries, F0, sL, sH);
        uint2 pL = pack4(sL), pH = pack4(sH);
        *reinterpret_cast<uint4*>(H1 + (size_t)row * DIM + l8 * 8) =
            make_uint4(pL.x, pL.y, pH.x, pH.y);
    } else {
        int t = (bid - AB8) * 256 + threadIdx.x;
        if (t >= NOUT) return;
        int bucket = out_bucket(t, users, pos, neg);
        flags[bucket] = 1;
        int beg = rp[bucket], end = rp[bucket + 1];
        for (int k = beg; k < end; ++k)
            flags[entries[k].x] = 1;
    }
}

// ---------------- compact flags -> row list ----------------
__global__ void compact_kernel(const int* __restrict__ flags,
                               int* __restrict__ list,
                               int* __restrict__ count)
{
    int t = blockIdx.x * blockDim.x + threadIdx.x;
    int idx = t * 4;
    if (idx >= NTOT) return;
    int4 f = *reinterpret_cast<const int4*>(flags + idx);
    int loc[4]; int k = 0;
    if (f.x) loc[k++] = idx;
    if (f.y) loc[k++] = idx + 1;
    if (f.z) loc[k++] = idx + 2;
    if (f.w) loc[k++] = idx + 3;
    if (k) {
        int base = atomicAdd(count, k);
        for (int m = 0; m < k; ++m) list[base + m] = loc[m];
    }
}

// ---------------- layer 2 (listed rows only) + out += 0.25*H1 ----------------
__global__ void agg2_add1_kernel(const int* __restrict__ rp,
                                 const int2* __restrict__ entries,
                                 const unsigned short* __restrict__ H1,
                                 unsigned short* __restrict__ H2,
                                 const int* __restrict__ list,
                                 const int* __restrict__ count,
                                 const int* __restrict__ users,
                                 const int* __restrict__ pos,
                                 const int* __restrict__ neg,
                                 float* __restrict__ out)
{
    int bid = blockIdx.x;
    if (bid < AB8) {
        int gid = bid * 256 + threadIdx.x;
        int lane = gid & 63;
        int l8 = lane & 7;
        int gb = lane & 56;
        int idx = gid >> 3;
        int n = *count;
        if (idx >= n) return;
        int row = list[idx];
        float4 sL, sH;
        agg_row8(row, l8, gb, rp, entries, H1, sL, sH);
        uint2 pL = pack4(sL), pH = pack4(sH);
        *reinterpret_cast<uint4*>(H2 + (size_t)row * DIM + l8 * 8) =
            make_uint4(pL.x, pL.y, pH.x, pH.y);
    } else {
        // out += 0.25 * H1[bucket], 8 floats/thread (matches OB = NOUT*8/256)
        int idx = (bid - AB8) * 256 + threadIdx.x;   // [0, NOUT*8)
        int row = idx >> 3;
        if (row >= NOUT) return;
        int d8 = (idx & 7) << 3;
        int bucket = out_bucket(row, users, pos, neg);
        uint4 v = *reinterpret_cast<const uint4*>(H1 + (size_t)bucket * DIM + d8);
        float* op = out + (size_t)row * DIM + d8;
        float4 o0 = *reinterpret_cast<const float4*>(op);
        float4 o1 = *reinterpret_cast<const float4*>(op + 4);
        o0.x += 0.25f * __uint_as_float(v.x << 16);
        o0.y += 0.25f * __uint_as_float(v.x & 0xffff0000u);
        o0.z += 0.25f * __uint_as_float(v.y << 16);
        o0.w += 0.25f * __uint_as_float(v.y & 0xffff0000u);
        o1.x += 0.25f * __uint_as_float(v.z << 16);
        o1.y += 0.25f * __uint_as_float(v.z & 0xffff0000u);
        o1.z += 0.25f * __uint_as_float(v.w << 16);
        o1.w += 0.25f * __uint_as_float(v.w & 0xffff0000u);
        *reinterpret_cast<float4*>(op) = o0;
        *reinterpret_cast<float4*>(op + 4) = o1;
    }
}

// ---------------- layer 3 at output rows, H2 add fused IN-THREAD ----------------
__global__ void aggout_add2_kernel(const int* __restrict__ rp,
                                   const int2* __restrict__ entries,
                                   const unsigned short* __restrict__ H2,
                                   const int* __restrict__ users,
                                   const int* __restrict__ pos,
                                   const int* __restrict__ neg,
                                   float* __restrict__ out)
{
    int gid = blockIdx.x * 256 + threadIdx.x;
    int lane = gid & 63;
    int l8 = lane & 7;
    int gb = lane & 56;
    int orow = gid >> 3;
    if (orow >= NOUT) return;
    int bucket = out_bucket(orow, users, pos, neg);
    float4 sL, sH;
    agg_row8(bucket, l8, gb, rp, entries, H2, sL, sH);
    uint4 v = *reinterpret_cast<const uint4*>(H2 + (size_t)bucket * DIM + l8 * 8);
    sL.x += __uint_as_float(v.x << 16);
    sL.y += __uint_as_float(v.x & 0xffff0000u);
    sL.z += __uint_as_float(v.y << 16);
    sL.w += __uint_as_float(v.y & 0xffff0000u);
    sH.x += __uint_as_float(v.z << 16);
    sH.y += __uint_as_float(v.z & 0xffff0000u);
    sH.z += __uint_as_float(v.w << 16);
    sH.w += __uint_as_float(v.w & 0xffff0000u);
    float* op = out + (size_t)orow * DIM + l8 * 8;
    float4 o0 = *reinterpret_cast<const float4*>(op);
    float4 o1 = *reinterpret_cast<const float4*>(op + 4);
    o0.x += 0.25f * sL.x; o0.y += 0.25f * sL.y;
    o0.z += 0.25f * sL.z; o0.w += 0.25f * sL.w;
    o1.x += 0.25f * sH.x; o1.y += 0.25f * sH.y;
    o1.z += 0.25f * sH.z; o1.w += 0.25f * sH.w;
    *reinterpret_cast<float4*>(op) = o0;
    *reinterpret_cast<float4*>(op + 4) = o1;
}

extern "C" void kernel_launch(void* const* d_in, const int* in_sizes, int n_in,
                              void* d_out, int out_size, void* d_ws, size_t ws_size,
                              hipStream_t stream)
{
    const float* user_feat = (const float*)d_in[0];
    const float* item_feat = (const float*)d_in[1];
    const int*   eu        = (const int*)d_in[2];
    const int*   ei        = (const int*)d_in[3];
    const float* norm      = (const float*)d_in[4];
    const int*   users     = (const int*)d_in[5];
    const int*   pos       = (const int*)d_in[6];
    const int*   neg       = (const int*)d_in[7];
    float* out = (float*)d_out;

    auto align256 = [](size_t x) { return (x + 255) & ~(size_t)255; };
    const size_t hBytes = (size_t)NTOT * DIM * sizeof(unsigned short);  // 38.4 MB

    char* p = (char*)d_ws;
    unsigned short* F0 = (unsigned short*)p; p += align256(hBytes);
    unsigned short* H1 = (unsigned short*)p; p += align256(hBytes);
    unsigned short* H2 = (unsigned short*)p; p += align256(hBytes);
    // memset region: partTotals(512 pad) | flags(NTOT) | count(16 pad)
    int* partTotals = (int*)p; p += align256((size_t)(512 + NTOT + 16) * 4);
    int* flags = partTotals + 512;
    int* count = flags + NTOT;
    int*  partStart = (int*)p;  p += align256(512 * 4);
    int*  gcur      = (int*)p;  p += align256(512 * 4);
    int*  rp        = (int*)p;  p += align256((size_t)(NTOT + 1) * 4);
    uint2* partBuf  = (uint2*)p; p += align256((size_t)2 * N_EDGES * 8);
    int*  list      = (int*)p;  p += align256((size_t)NTOT * 4);
    int2* entries   = (int2*)p; p += align256((size_t)2 * N_EDGES * 8);
    // total ~150 MB

    hipMemsetAsync(partTotals, 0, (size_t)(512 + NTOT + 16) * 4, stream);

    // A: partition hist only (short critical-path head)
    hist_kernel<<<HA, 256, 0, stream>>>(eu, ei, partTotals);

    // S: scan partition totals
    part_scan_kernel<<<1, 512, 0, stream>>>(partTotals, partStart, gcur);

    // B: partition scatter + f32->bf16 convert + out_h0 (overlapped)
    partition_conv_kernel<<<HA + CB + OB, 256, 0, stream>>>(
        eu, ei, norm, gcur, partBuf,
        (const float4*)user_feat, (const float4*)item_feat, F0,
        user_feat, item_feat, users, pos, neg, out);

    // C: per-partition CSR build (writes rp + entries), 1024 thr/block
    build_csr_kernel<<<NPART, 1024, 0, stream>>>(partStart, partBuf, rp, entries);

    // layer 1 (all rows) + flag scatter for needed-H2 set
    agg1_flag_kernel<<<AB8 + FB, 256, 0, stream>>>(
        rp, entries, F0, H1, users, pos, neg, flags);

    compact_kernel<<<(NTOT / 4 + 255) / 256, 256, 0, stream>>>(flags, list, count);

    // layer 2 (listed rows) + out += 0.25*H1
    agg2_add1_kernel<<<AB8 + OB, 256, 0, stream>>>(
        rp, entries, H1, H2, list, count, users, pos, neg, out);

    // layer 3 at output rows with in-thread H2 add
    aggout_add2_kernel<<<NOUT / 32, 256, 0, stream>>>(
        rp, entries, H2, users, pos, neg, out);
}

// Round 6
// 284.033 us; speedup vs baseline: 1.4074x; 1.0027x over previous
//
#include <hip/hip_runtime.h>

// LightGCN propagation, CSR-gather, bf16 intermediates, unified row space.
// R15 (from R14 @284us):
//  - Diagnosis: R12 (occ 54%) == R14 (occ 34%) perf -> NOT occupancy-bound;
//    per-wave gather rounds serialize because the default VGPR budget (32-48)
//    can't hold 8 in-flight dwordx4 loads. ~9100 cy/wave for 2-3 rounds.
//  - Fix: __launch_bounds__(256,2) on agg kernels (VGPR cap 256) + phase-split
//    rounds: [16 shuffles] -> [8 loads into uint4 v[8]] -> [16 fma4], fully
//    unrolled static indexing. All 8 gathers batch into one vmcnt group.
//  - Pipeline otherwise identical to R14.

#define N_USERS 200000
#define N_ITEMS 100000
#define N_EDGES 1000000
#define DIM 64
#define BATCH 8192
#define NTOT (N_USERS + N_ITEMS)          // 300000 rows
#define NOUT (3 * BATCH)                  // 24576 output rows
#define NPART 293                         // ceil(NTOT / 1024)
#define PLOCAL 1024

#define HA 489                            // hist/partition blocks: 8 edges/thread
#define NUNITS (NTOT * DIM / 8)           // 2.4M 8-float convert units
#define CB ((NUNITS + 1023) / 1024)       // 2344 convert blocks (32 floats/thread)
#define OB (NOUT * 8 / 256)               // 768 out_h0 / add1 blocks (8 floats/thread)
#define AB8 (NTOT / 32)                   // 9375 agg blocks (32 rows/block, 8 lanes/row)
#define FB ((NOUT + 255) / 256)           // 96 flag-scatter blocks

// ---------- bf16 helpers ----------
__device__ __forceinline__ unsigned f2bf(float f) {   // round-to-nearest-even
    unsigned u = __float_as_uint(f);
    return (u + 0x7fffu + ((u >> 16) & 1u)) >> 16;
}
__device__ __forceinline__ uint2 pack4(float4 v) {
    uint2 o;
    o.x = f2bf(v.x) | (f2bf(v.y) << 16);
    o.y = f2bf(v.z) | (f2bf(v.w) << 16);
    return o;
}
__device__ __forceinline__ void fma4(float4& a, uint2 v, float w) {
    a.x += __uint_as_float(v.x << 16) * w;
    a.y += __uint_as_float(v.x & 0xffff0000u) * w;
    a.z += __uint_as_float(v.y << 16) * w;
    a.w += __uint_as_float(v.y & 0xffff0000u) * w;
}
__device__ __forceinline__ int out_bucket(int orow, const int* users,
                                          const int* pos, const int* neg) {
    int seg = orow >> 13;
    int b = orow & (BATCH - 1);
    if (seg == 0) return users[b];
    if (seg == 1) return N_USERS + pos[b];
    return N_USERS + neg[b];
}

// ---------------- A: partition hist only ----------------
__global__ void hist_kernel(const int* __restrict__ eu,
                            const int* __restrict__ ei,
                            int* __restrict__ partTotals)
{
    __shared__ int lh[NPART];
    int bid = blockIdx.x;
    for (int k = threadIdx.x; k < NPART; k += 256) lh[k] = 0;
    __syncthreads();
    int e0 = (bid * 256 + threadIdx.x) * 8;
    if (e0 < N_EDGES) {
        int4 u0 = *reinterpret_cast<const int4*>(eu + e0);
        int4 u1 = *reinterpret_cast<const int4*>(eu + e0 + 4);
        int4 i0 = *reinterpret_cast<const int4*>(ei + e0);
        int4 i1 = *reinterpret_cast<const int4*>(ei + e0 + 4);
        atomicAdd(&lh[u0.x >> 10], 1);
        atomicAdd(&lh[u0.y >> 10], 1);
        atomicAdd(&lh[u0.z >> 10], 1);
        atomicAdd(&lh[u0.w >> 10], 1);
        atomicAdd(&lh[u1.x >> 10], 1);
        atomicAdd(&lh[u1.y >> 10], 1);
        atomicAdd(&lh[u1.z >> 10], 1);
        atomicAdd(&lh[u1.w >> 10], 1);
        atomicAdd(&lh[(N_USERS + i0.x) >> 10], 1);
        atomicAdd(&lh[(N_USERS + i0.y) >> 10], 1);
        atomicAdd(&lh[(N_USERS + i0.z) >> 10], 1);
        atomicAdd(&lh[(N_USERS + i0.w) >> 10], 1);
        atomicAdd(&lh[(N_USERS + i1.x) >> 10], 1);
        atomicAdd(&lh[(N_USERS + i1.y) >> 10], 1);
        atomicAdd(&lh[(N_USERS + i1.z) >> 10], 1);
        atomicAdd(&lh[(N_USERS + i1.w) >> 10], 1);
    }
    __syncthreads();
    for (int k = threadIdx.x; k < NPART; k += 256) {
        int v = lh[k];
        if (v) atomicAdd(&partTotals[k], v);   // fire-and-forget
    }
}

// ---------------- S: scan partition totals ----------------
__global__ void part_scan_kernel(const int* __restrict__ partTotals,
                                 int* __restrict__ partStart,
                                 int* __restrict__ gcur)
{
    __shared__ int s[512];
    int t = threadIdx.x;
    s[t] = (t < NPART) ? partTotals[t] : 0;
    __syncthreads();
    for (int off = 1; off < 512; off <<= 1) {
        int x = (t >= off) ? s[t - off] : 0;
        __syncthreads();
        s[t] += x;
        __syncthreads();
    }
    if (t < NPART) {
        int st = (t == 0) ? 0 : s[t - 1];
        partStart[t] = st;
        gcur[t] = st;
    }
    if (t == NPART) partStart[NPART] = s[NPART - 1];   // == 2*N_EDGES
}

// ---------------- B: partition scatter + convert + out_h0 ----------------
// record meta = (bucket & 1023) | (col << 10);  col < 2^19, total 29 bits.
__global__ void partition_conv_kernel(const int* __restrict__ eu,
                                      const int* __restrict__ ei,
                                      const float* __restrict__ w,
                                      int* __restrict__ gcur,
                                      uint2* __restrict__ partBuf,
                                      const float4* __restrict__ uf4,
                                      const float4* __restrict__ if4,
                                      unsigned short* __restrict__ F0,
                                      const float* __restrict__ u_feat,
                                      const float* __restrict__ i_feat,
                                      const int* __restrict__ users,
                                      const int* __restrict__ pos,
                                      const int* __restrict__ neg,
                                      float* __restrict__ out)
{
    int bid = blockIdx.x, t = threadIdx.x;
    if (bid < HA) {
        __shared__ int lh[NPART];
        __shared__ int lcur[NPART];
        for (int k = t; k < NPART; k += 256) lh[k] = 0;
        __syncthreads();
        int e0 = (bid * 256 + t) * 8;
        bool act = e0 < N_EDGES;
        int4 u0, u1, i0, i1;
        if (act) {
            u0 = *reinterpret_cast<const int4*>(eu + e0);
            u1 = *reinterpret_cast<const int4*>(eu + e0 + 4);
            i0 = *reinterpret_cast<const int4*>(ei + e0);
            i1 = *reinterpret_cast<const int4*>(ei + e0 + 4);
            atomicAdd(&lh[u0.x >> 10], 1);
            atomicAdd(&lh[u0.y >> 10], 1);
            atomicAdd(&lh[u0.z >> 10], 1);
            atomicAdd(&lh[u0.w >> 10], 1);
            atomicAdd(&lh[u1.x >> 10], 1);
            atomicAdd(&lh[u1.y >> 10], 1);
            atomicAdd(&lh[u1.z >> 10], 1);
            atomicAdd(&lh[u1.w >> 10], 1);
            atomicAdd(&lh[(N_USERS + i0.x) >> 10], 1);
            atomicAdd(&lh[(N_USERS + i0.y) >> 10], 1);
            atomicAdd(&lh[(N_USERS + i0.z) >> 10], 1);
            atomicAdd(&lh[(N_USERS + i0.w) >> 10], 1);
            atomicAdd(&lh[(N_USERS + i1.x) >> 10], 1);
            atomicAdd(&lh[(N_USERS + i1.y) >> 10], 1);
            atomicAdd(&lh[(N_USERS + i1.z) >> 10], 1);
            atomicAdd(&lh[(N_USERS + i1.w) >> 10], 1);
        }
        __syncthreads();
        // reserve: one returning atomic per (block, nonempty partition)
        for (int k = t; k < NPART; k += 256) {
            int v = lh[k];
            lcur[k] = v ? atomicAdd(&gcur[k], v) : 0;
        }
        __syncthreads();
        if (act) {
            float4 wa = *reinterpret_cast<const float4*>(w + e0);
            float4 wb = *reinterpret_cast<const float4*>(w + e0 + 4);
            int us[8] = {u0.x, u0.y, u0.z, u0.w, u1.x, u1.y, u1.z, u1.w};
            int is[8] = {i0.x, i0.y, i0.z, i0.w, i1.x, i1.y, i1.z, i1.w};
            float ws[8] = {wa.x, wa.y, wa.z, wa.w, wb.x, wb.y, wb.z, wb.w};
            #pragma unroll
            for (int j = 0; j < 8; ++j) {
                int bu = us[j];
                int bi = N_USERS + is[j];
                unsigned wbits = __float_as_uint(ws[j]);
                int su = atomicAdd(&lcur[bu >> 10], 1);    // LDS
                partBuf[su] = make_uint2((unsigned)(bu & 1023) | ((unsigned)bi << 10), wbits);
                int si = atomicAdd(&lcur[bi >> 10], 1);    // LDS
                partBuf[si] = make_uint2((unsigned)(bi & 1023) | ((unsigned)bu << 10), wbits);
            }
        }
    } else if (bid < HA + CB) {
        // f32 -> bf16 convert, 32 floats/thread, 8 loads batched in flight.
        const int NU4 = N_USERS * DIM / 4;           // 3.2M float4s (user side)
        int jb = (bid - HA) * 1024 + t;              // 8-float unit index, round 0
        float4 a[4], b[4];
        #pragma unroll
        for (int c = 0; c < 4; ++c) {
            int j = jb + c * 256;
            if (j < NUNITS) {
                int f4 = j * 2;
                if (f4 < NU4) { a[c] = uf4[f4];       b[c] = uf4[f4 + 1]; }
                else          { a[c] = if4[f4 - NU4]; b[c] = if4[f4 - NU4 + 1]; }
            }
        }
        #pragma unroll
        for (int c = 0; c < 4; ++c) {
            int j = jb + c * 256;
            if (j < NUNITS) {
                uint2 pa = pack4(a[c]), pb = pack4(b[c]);
                *reinterpret_cast<uint4*>(F0 + (size_t)j * 8) =
                    make_uint4(pa.x, pa.y, pb.x, pb.y);
            }
        }
    } else {
        // out = 0.25 * h0 at gathered rows, 8 floats/thread (2 loads in flight)
        int idx = (bid - HA - CB) * 256 + t;         // [0, NOUT*8) exactly
        int row = idx >> 3;
        if (row >= NOUT) return;
        int d8 = (idx & 7) << 3;
        int seg = row >> 13;
        int b = row & (BATCH - 1);
        const float* src;
        if (seg == 0)      src = u_feat + (size_t)users[b] * DIM;
        else if (seg == 1) src = i_feat + (size_t)pos[b]   * DIM;
        else               src = i_feat + (size_t)neg[b]   * DIM;
        float4 v0 = *reinterpret_cast<const float4*>(src + d8);
        float4 v1 = *reinterpret_cast<const float4*>(src + d8 + 4);
        v0.x *= 0.25f; v0.y *= 0.25f; v0.z *= 0.25f; v0.w *= 0.25f;
        v1.x *= 0.25f; v1.y *= 0.25f; v1.z *= 0.25f; v1.w *= 0.25f;
        float* op = out + (size_t)row * DIM + d8;
        *reinterpret_cast<float4*>(op) = v0;
        *reinterpret_cast<float4*>(op + 4) = v1;
    }
}

// ---------------- C: per-partition CSR build (rp + entries) ----------------
__global__ void __launch_bounds__(1024)
build_csr_kernel(const int* __restrict__ partStart,
                 const uint2* __restrict__ partBuf,
                 int* __restrict__ rp,
                 int2* __restrict__ entries)
{
    __shared__ int h[PLOCAL];
    __shared__ int s[PLOCAL];
    __shared__ int cur[PLOCAL];
    int p = blockIdx.x, t = threadIdx.x;
    int base = partStart[p], end = partStart[p + 1];
    h[t] = 0;
    __syncthreads();
    for (int r = base + t; r < end; r += 1024)
        atomicAdd(&h[partBuf[r].x & 1023], 1);
    __syncthreads();
    s[t] = h[t];
    __syncthreads();
    for (int off = 1; off < 1024; off <<= 1) {
        int x = (t >= off) ? s[t - off] : 0;
        __syncthreads();
        s[t] += x;
        __syncthreads();
    }
    int c0 = base + s[t] - h[t];        // exclusive scan -> bucket start
    cur[t] = c0;
    int gb = p * PLOCAL + t;
    if (gb <= NTOT) rp[gb] = c0;
    __syncthreads();
    for (int r = base + t; r < end; r += 1024) {
        uint2 rec = partBuf[r];
        int slot = atomicAdd(&cur[rec.x & 1023], 1);   // LDS
        entries[slot] = make_int2((int)(rec.x >> 10), (int)rec.y);
    }
}

// ---------------- agg core: phase-split rounds, 8 lanes/row ----------------
// Per round: [16 shuffles] -> [8 dwordx4 loads into v[8]] -> [16 fma4].
// All loads independent & batched into one vmcnt group (32 VGPR of data;
// kernels carry __launch_bounds__(256,2) so the allocator doesn't squeeze).
// Masked slots: e={0,0} -> row 0, w=0.0 -> exact +0, L1-hot.
__device__ __forceinline__ void agg_row8(int row, int l8, int gb,
                                         const int* __restrict__ rp,
                                         const int2* __restrict__ entries,
                                         const unsigned short* __restrict__ src,
                                         float4& sL, float4& sH)
{
    int beg = rp[row], cnt = rp[row + 1] - beg;
    float4 a0L = {0,0,0,0}, a0H = {0,0,0,0}, a1L = {0,0,0,0}, a1H = {0,0,0,0};
    for (int base = 0; base < cnt; base += 8) {
        int2 e = make_int2(0, 0);
        if (base + l8 < cnt) e = entries[beg + base + l8];
        int   c[8];
        float wv[8];
        #pragma unroll
        for (int k = 0; k < 8; ++k) {
            c[k]  = __shfl(e.x, gb + k);
            wv[k] = __int_as_float(__shfl(e.y, gb + k));
        }
        uint4 v[8];
        #pragma unroll
        for (int k = 0; k < 8; ++k)
            v[k] = *reinterpret_cast<const uint4*>(
                src + (size_t)c[k] * DIM + l8 * 8);
        #pragma unroll
        for (int k = 0; k < 8; ++k) {
            if (k & 1) {
                fma4(a1L, make_uint2(v[k].x, v[k].y), wv[k]);
                fma4(a1H, make_uint2(v[k].z, v[k].w), wv[k]);
            } else {
                fma4(a0L, make_uint2(v[k].x, v[k].y), wv[k]);
                fma4(a0H, make_uint2(v[k].z, v[k].w), wv[k]);
            }
        }
    }
    sL.x = a0L.x + a1L.x; sL.y = a0L.y + a1L.y;
    sL.z = a0L.z + a1L.z; sL.w = a0L.w + a1L.w;
    sH.x = a0H.x + a1H.x; sH.y = a0H.y + a1H.y;
    sH.z = a0H.z + a1H.z; sH.w = a0H.w + a1H.w;
}

// ---------------- layer 1 (all rows) + flag scatter ----------------
__global__ void __launch_bounds__(256, 2)
agg1_flag_kernel(const int* __restrict__ rp,
                 const int2* __restrict__ entries,
                 const unsigned short* __restrict__ F0,
                 unsigned short* __restrict__ H1,
                 const int* __restrict__ users,
                 const int* __restrict__ pos,
                 const int* __restrict__ neg,
                 int* __restrict__ flags)
{
    int bid = blockIdx.x;
    if (bid < AB8) {
        int gid = bid * 256 + threadIdx.x;
        int lane = gid & 63;
        int l8 = lane & 7;
        int gb = lane & 56;
        int row = gid >> 3;
        if (row >= NTOT) return;
        float4 sL, sH;
        agg_row8(row, l8, gb, rp, entries, F0, sL, sH);
        uint2 pL = pack4(sL), pH = pack4(sH);
        *reinterpret_cast<uint4*>(H1 + (size_t)row * DIM + l8 * 8) =
            make_uint4(pL.x, pL.y, pH.x, pH.y);
    } else {
        int t = (bid - AB8) * 256 + threadIdx.x;
        if (t >= NOUT) return;
        int bucket = out_bucket(t, users, pos, neg);
        flags[bucket] = 1;
        int beg = rp[bucket], end = rp[bucket + 1];
        for (int k = beg; k < end; ++k)
            flags[entries[k].x] = 1;
    }
}

// ---------------- compact flags -> row list ----------------
__global__ void compact_kernel(const int* __restrict__ flags,
                               int* __restrict__ list,
                               int* __restrict__ count)
{
    int t = blockIdx.x * blockDim.x + threadIdx.x;
    int idx = t * 4;
    if (idx >= NTOT) return;
    int4 f = *reinterpret_cast<const int4*>(flags + idx);
    int loc[4]; int k = 0;
    if (f.x) loc[k++] = idx;
    if (f.y) loc[k++] = idx + 1;
    if (f.z) loc[k++] = idx + 2;
    if (f.w) loc[k++] = idx + 3;
    if (k) {
        int base = atomicAdd(count, k);
        for (int m = 0; m < k; ++m) list[base + m] = loc[m];
    }
}

// ---------------- layer 2 (listed rows only) + out += 0.25*H1 ----------------
__global__ void __launch_bounds__(256, 2)
agg2_add1_kernel(const int* __restrict__ rp,
                 const int2* __restrict__ entries,
                 const unsigned short* __restrict__ H1,
                 unsigned short* __restrict__ H2,
                 const int* __restrict__ list,
                 const int* __restrict__ count,
                 const int* __restrict__ users,
                 const int* __restrict__ pos,
                 const int* __restrict__ neg,
                 float* __restrict__ out)
{
    int bid = blockIdx.x;
    if (bid < AB8) {
        int gid = bid * 256 + threadIdx.x;
        int lane = gid & 63;
        int l8 = lane & 7;
        int gb = lane & 56;
        int idx = gid >> 3;
        int n = *count;
        if (idx >= n) return;
        int row = list[idx];
        float4 sL, sH;
        agg_row8(row, l8, gb, rp, entries, H1, sL, sH);
        uint2 pL = pack4(sL), pH = pack4(sH);
        *reinterpret_cast<uint4*>(H2 + (size_t)row * DIM + l8 * 8) =
            make_uint4(pL.x, pL.y, pH.x, pH.y);
    } else {
        // out += 0.25 * H1[bucket], 8 floats/thread (matches OB = NOUT*8/256)
        int idx = (bid - AB8) * 256 + threadIdx.x;   // [0, NOUT*8)
        int row = idx >> 3;
        if (row >= NOUT) return;
        int d8 = (idx & 7) << 3;
        int bucket = out_bucket(row, users, pos, neg);
        uint4 v = *reinterpret_cast<const uint4*>(H1 + (size_t)bucket * DIM + d8);
        float* op = out + (size_t)row * DIM + d8;
        float4 o0 = *reinterpret_cast<const float4*>(op);
        float4 o1 = *reinterpret_cast<const float4*>(op + 4);
        o0.x += 0.25f * __uint_as_float(v.x << 16);
        o0.y += 0.25f * __uint_as_float(v.x & 0xffff0000u);
        o0.z += 0.25f * __uint_as_float(v.y << 16);
        o0.w += 0.25f * __uint_as_float(v.y & 0xffff0000u);
        o1.x += 0.25f * __uint_as_float(v.z << 16);
        o1.y += 0.25f * __uint_as_float(v.z & 0xffff0000u);
        o1.z += 0.25f * __uint_as_float(v.w << 16);
        o1.w += 0.25f * __uint_as_float(v.w & 0xffff0000u);
        *reinterpret_cast<float4*>(op) = o0;
        *reinterpret_cast<float4*>(op + 4) = o1;
    }
}

// ---------------- layer 3 at output rows, H2 add fused IN-THREAD ----------------
__global__ void __launch_bounds__(256, 2)
aggout_add2_kernel(const int* __restrict__ rp,
                   const int2* __restrict__ entries,
                   const unsigned short* __restrict__ H2,
                   const int* __restrict__ users,
                   const int* __restrict__ pos,
                   const int* __restrict__ neg,
                   float* __restrict__ out)
{
    int gid = blockIdx.x * 256 + threadIdx.x;
    int lane = gid & 63;
    int l8 = lane & 7;
    int gb = lane & 56;
    int orow = gid >> 3;
    if (orow >= NOUT) return;
    int bucket = out_bucket(orow, users, pos, neg);
    float4 sL, sH;
    agg_row8(bucket, l8, gb, rp, entries, H2, sL, sH);
    uint4 v = *reinterpret_cast<const uint4*>(H2 + (size_t)bucket * DIM + l8 * 8);
    sL.x += __uint_as_float(v.x << 16);
    sL.y += __uint_as_float(v.x & 0xffff0000u);
    sL.z += __uint_as_float(v.y << 16);
    sL.w += __uint_as_float(v.y & 0xffff0000u);
    sH.x += __uint_as_float(v.z << 16);
    sH.y += __uint_as_float(v.z & 0xffff0000u);
    sH.z += __uint_as_float(v.w << 16);
    sH.w += __uint_as_float(v.w & 0xffff0000u);
    float* op = out + (size_t)orow * DIM + l8 * 8;
    float4 o0 = *reinterpret_cast<const float4*>(op);
    float4 o1 = *reinterpret_cast<const float4*>(op + 4);
    o0.x += 0.25f * sL.x; o0.y += 0.25f * sL.y;
    o0.z += 0.25f * sL.z; o0.w += 0.25f * sL.w;
    o1.x += 0.25f * sH.x; o1.y += 0.25f * sH.y;
    o1.z += 0.25f * sH.z; o1.w += 0.25f * sH.w;
    *reinterpret_cast<float4*>(op) = o0;
    *reinterpret_cast<float4*>(op + 4) = o1;
}

extern "C" void kernel_launch(void* const* d_in, const int* in_sizes, int n_in,
                              void* d_out, int out_size, void* d_ws, size_t ws_size,
                              hipStream_t stream)
{
    const float* user_feat = (const float*)d_in[0];
    const float* item_feat = (const float*)d_in[1];
    const int*   eu        = (const int*)d_in[2];
    const int*   ei        = (const int*)d_in[3];
    const float* norm      = (const float*)d_in[4];
    const int*   users     = (const int*)d_in[5];
    const int*   pos       = (const int*)d_in[6];
    const int*   neg       = (const int*)d_in[7];
    float* out = (float*)d_out;

    auto align256 = [](size_t x) { return (x + 255) & ~(size_t)255; };
    const size_t hBytes = (size_t)NTOT * DIM * sizeof(unsigned short);  // 38.4 MB

    char* p = (char*)d_ws;
    unsigned short* F0 = (unsigned short*)p; p += align256(hBytes);
    unsigned short* H1 = (unsigned short*)p; p += align256(hBytes);
    unsigned short* H2 = (unsigned short*)p; p += align256(hBytes);
    // memset region: partTotals(512 pad) | flags(NTOT) | count(16 pad)
    int* partTotals = (int*)p; p += align256((size_t)(512 + NTOT + 16) * 4);
    int* flags = partTotals + 512;
    int* count = flags + NTOT;
    int*  partStart = (int*)p;  p += align256(512 * 4);
    int*  gcur      = (int*)p;  p += align256(512 * 4);
    int*  rp        = (int*)p;  p += align256((size_t)(NTOT + 1) * 4);
    uint2* partBuf  = (uint2*)p; p += align256((size_t)2 * N_EDGES * 8);
    int*  list      = (int*)p;  p += align256((size_t)NTOT * 4);
    int2* entries   = (int2*)p; p += align256((size_t)2 * N_EDGES * 8);
    // total ~150 MB

    hipMemsetAsync(partTotals, 0, (size_t)(512 + NTOT + 16) * 4, stream);

    // A: partition hist only (short critical-path head)
    hist_kernel<<<HA, 256, 0, stream>>>(eu, ei, partTotals);

    // S: scan partition totals
    part_scan_kernel<<<1, 512, 0, stream>>>(partTotals, partStart, gcur);

    // B: partition scatter + f32->bf16 convert + out_h0 (overlapped)
    partition_conv_kernel<<<HA + CB + OB, 256, 0, stream>>>(
        eu, ei, norm, gcur, partBuf,
        (const float4*)user_feat, (const float4*)item_feat, F0,
        user_feat, item_feat, users, pos, neg, out);

    // C: per-partition CSR build (writes rp + entries), 1024 thr/block
    build_csr_kernel<<<NPART, 1024, 0, stream>>>(partStart, partBuf, rp, entries);

    // layer 1 (all rows) + flag scatter for needed-H2 set
    agg1_flag_kernel<<<AB8 + FB, 256, 0, stream>>>(
        rp, entries, F0, H1, users, pos, neg, flags);

    compact_kernel<<<(NTOT / 4 + 255) / 256, 256, 0, stream>>>(flags, list, count);

    // layer 2 (listed rows) + out += 0.25*H1
    agg2_add1_kernel<<<AB8 + OB, 256, 0, stream>>>(
        rp, entries, H1, H2, list, count, users, pos, neg, out);

    // layer 3 at output rows with in-thread H2 add
    aggout_add2_kernel<<<NOUT / 32, 256, 0, stream>>>(
        rp, entries, H2, users, pos, neg, out);
}